// Round 1
// baseline (1784.981 us; speedup 1.0000x reference)
//
#include <hip/hip_runtime.h>

#define EN 1536     // edges == nodes
#define NG 64
#define F0V 12

typedef _Float16 half8_t __attribute__((ext_vector_type(8)));
typedef _Float16 half4_t __attribute__((ext_vector_type(4)));
typedef float f32x16 __attribute__((ext_vector_type(16)));
typedef unsigned int uint4_t __attribute__((ext_vector_type(4)));

__device__ __forceinline__ float lrelu(float v) { return v >= 0.f ? v : 0.01f * v; }

// ---------------- counts: edges per dst node, nodes per graph ----------------
__global__ void k_counts(const int* __restrict__ dst, const int* __restrict__ batch,
                         float* __restrict__ cntE, float* __restrict__ cntg) {
    int t = blockIdx.x * 256 + threadIdx.x;
    if (t < EN) {
        atomicAdd(&cntE[dst[t]], 1.f);
        atomicAdd(&cntg[batch[t]], 1.f);
    }
}

// ---------------- edge MLP first layer: z = leaky(ea@Wa+ba), stored as dup-packed f16 [K][E] ----
template<int K>
__global__ void k_edge_mlp(const float* __restrict__ ea, const float* __restrict__ Wa,
                           const float* __restrict__ ba, unsigned* __restrict__ zdup) {
    int idx = blockIdx.x * 256 + threadIdx.x;
    int e = idx % EN, k = idx / EN;
    if (k >= K) return;
    float u = ba[k];
#pragma unroll
    for (int a = 0; a < 4; ++a) u += ea[e * 4 + a] * Wa[a * K + k];
    u = lrelu(u);
    _Float16 h = (_Float16)u;
    unsigned short us = __builtin_bit_cast(unsigned short, h);
    zdup[(size_t)k * EN + e] = (unsigned)us * 0x10001u;
}

// ---------------- gather src features to f16, padded [E][IPAD] ----------------
template<int IPAD, int IACT>
__global__ void k_gather(const float* __restrict__ feat, const int* __restrict__ src,
                         _Float16* __restrict__ xs) {
    int idx = blockIdx.x * 256 + threadIdx.x;
    int e = idx / IPAD, i = idx % IPAD;
    float v = (i < IACT) ? feat[(size_t)src[e] * IACT + i] : 0.f;
    xs[idx] = (_Float16)v;
}

// ---------------- scatter-add gathered features by dst: S[n,i] = sum_{dst(e)=n} feat[src(e),i] ----
template<int IW>
__global__ void k_scatter(const float* __restrict__ feat, const int* __restrict__ src,
                          const int* __restrict__ dst, float* __restrict__ S) {
    int idx = blockIdx.x * 256 + threadIdx.x;
    int e = idx / IW, i = idx % IW;
    atomicAdd(&S[(size_t)dst[e] * IW + i], feat[(size_t)src[e] * IW + i]);
}

// ---------------- big fused edge-message GEMM ----------------
// msg[e,o] = sum_k sum_i z[e,k]*xs[e,i]*Bw[k, i*O+o], atomically scattered into accG[dst[e], o].
// Virtual K-dim = (k outer, i inner). A-fragments built in registers: xs-frag (held across k) * z scalar.
template<int KTOT, int O, int IACT, int NIQ, int IC>
__global__ __launch_bounds__(512, 2)
void edge_gemm(const float* __restrict__ Bw, const unsigned* __restrict__ zdup,
               const _Float16* __restrict__ xs, const int* __restrict__ dstIdx,
               float* __restrict__ accG) {
    constexpr int IPAD = NIQ * IC;
    constexpr int NI0 = IC / 16;   // 16-i MFMA chunks per staged tile
    constexpr int RPT = IC / 4;    // B rows per staging thread

    __shared__ _Float16 xsL[NI0 * 8 * 512];  // frag-ordered xs tiles
    __shared__ _Float16 BL[NI0 * 8 * 512];   // frag-ordered B tile (one k)
    __shared__ unsigned zL[16 * 256];        // z dup-pairs for a 16-k chunk
    __shared__ int dstL[256];

    const int t = threadIdx.x;
    const int lane = t & 63;
    const int w = t >> 6, wm = w >> 1, wn = w & 1;   // 4 m-waves x 2 n-waves
    const int mt = blockIdx.x, nt = blockIdx.y;
    const int e0 = mt * 256, n0 = nt * 256;
    const int k0 = (KTOT * blockIdx.z) / gridDim.z;
    const int k1 = (KTOT * (blockIdx.z + 1)) / gridDim.z;

    if (t < 256) dstL[t] = dstIdx[e0 + t];

    f32x16 acc[2][4] = {};

    // B staging mapping: 2 n-cols per thread, RPT i-rows
    const int nn = 2 * (t & 127);
    const int ig = t >> 7;

    for (int iq = 0; iq < NIQ; ++iq) {
        __syncthreads();
        // stage xs tile (frag order): 2 threads per edge-row
        {
            const int e_loc = t >> 1, ihalf = t & 1;
            const _Float16* sp = xs + (size_t)(e0 + e_loc) * IPAD + iq * IC + ihalf * (IC / 2);
#pragma unroll
            for (int u = 0; u < IC / 16; ++u) {
                half8_t v = *(const half8_t*)(sp + u * 8);
                int i_loc = ihalf * (IC / 2) + u * 8;
                int i0 = i_loc >> 4, uu = (i_loc >> 3) & 1;
                *(half8_t*)(xsL + (size_t)(i0 * 8 + (e_loc >> 5)) * 512 + (uu * 32 + (e_loc & 31)) * 8) = v;
            }
        }
        __syncthreads();
        // load xs fragments into registers (live across entire k loop)
        half8_t xsr[NI0][2];
#pragma unroll
        for (int i0 = 0; i0 < NI0; ++i0)
#pragma unroll
            for (int mf = 0; mf < 2; ++mf)
                xsr[i0][mf] = *(const half8_t*)(xsL + (size_t)(i0 * 8 + wm * 2 + mf) * 512 + lane * 8);

        for (int kc = k0; kc < k1; kc += 16) {
            const int ck = (k1 - kc) < 16 ? (k1 - kc) : 16;
            __syncthreads();  // previous MFMA done before zL rewrite
            for (int idx = t; idx < ck * 256; idx += 512)
                zL[idx] = zdup[(size_t)(kc + (idx >> 8)) * EN + e0 + (idx & 255)];

            float2 pre[RPT];
            auto loadB = [&](float2* p, int k) {
#pragma unroll
                for (int j = 0; j < RPT; ++j) {
                    int ia = iq * IC + ig * RPT + j;
                    float2 v = {0.f, 0.f};
                    if (ia < IACT)
                        v = *(const float2*)(Bw + (size_t)k * IACT * O + (size_t)ia * O + n0 + nn);
                    p[j] = v;
                }
            };
            auto writeB = [&](float2* p) {
#pragma unroll
                for (int c = 0; c < 2; ++c) {
                    const int n = nn + c;
                    if constexpr (RPT == 16) {
                        half8_t v0, v1;
#pragma unroll
                        for (int j = 0; j < 8; ++j) {
                            v0[j] = (_Float16)(c ? p[j].y : p[j].x);
                            v1[j] = (_Float16)(c ? p[j + 8].y : p[j + 8].x);
                        }
                        _Float16* bp = BL + (size_t)(ig * 8 + (n >> 5)) * 512 + (n & 31) * 8;
                        *(half8_t*)bp = v0;
                        *(half8_t*)(bp + 256) = v1;
                    } else {  // RPT == 4
                        half4_t v;
#pragma unroll
                        for (int j = 0; j < 4; ++j) v[j] = (_Float16)(c ? p[j].y : p[j].x);
                        int i = ig * 4;
                        int uu = i >> 3, off = i & 7;
                        *(half4_t*)(BL + (size_t)(n >> 5) * 512 + (uu * 32 + (n & 31)) * 8 + off) = v;
                    }
                }
            };

            loadB(pre, kc);
            for (int kk = 0; kk < ck; ++kk) {
                const int k = kc + kk;
                __syncthreads();            // MFMA(k-1) done; safe to overwrite BL
                writeB(pre);
                if (kk + 1 < ck) loadB(pre, k + 1);   // prefetch next k into regs
                __syncthreads();            // BL ready
                unsigned zd0 = zL[kk * 256 + wm * 64 + (lane & 31)];
                unsigned zd1 = zL[kk * 256 + wm * 64 + 32 + (lane & 31)];
                uint4_t u0 = {zd0, zd0, zd0, zd0}, u1 = {zd1, zd1, zd1, zd1};
                half8_t z0 = __builtin_bit_cast(half8_t, u0);
                half8_t z1 = __builtin_bit_cast(half8_t, u1);
#pragma unroll
                for (int i0 = 0; i0 < NI0; ++i0) {
                    half8_t a0 = xsr[i0][0] * z0;
                    half8_t a1 = xsr[i0][1] * z1;
#pragma unroll
                    for (int nf = 0; nf < 4; ++nf) {
                        half8_t b = *(const half8_t*)(BL + (size_t)(i0 * 8 + wn * 4 + nf) * 512 + lane * 8);
                        acc[0][nf] = __builtin_amdgcn_mfma_f32_32x32x16_f16(a0, b, acc[0][nf], 0, 0, 0);
                        acc[1][nf] = __builtin_amdgcn_mfma_f32_32x32x16_f16(a1, b, acc[1][nf], 0, 0, 0);
                    }
                }
            }
        }
    }

    // epilogue: fused segment-sum scatter (32x32 C layout: col=lane&31, row=(r&3)+8*(r>>2)+4*(lane>>5))
#pragma unroll
    for (int mf = 0; mf < 2; ++mf)
#pragma unroll
        for (int nf = 0; nf < 4; ++nf)
#pragma unroll
            for (int r = 0; r < 16; ++r) {
                int row = (r & 3) + 8 * (r >> 2) + 4 * (lane >> 5);
                int m = wm * 64 + mf * 32 + row;
                int o = wn * 128 + nf * 32 + (lane & 31);
                atomicAdd(&accG[(size_t)dstL[m] * O + n0 + o], acc[mf][nf][r]);
            }
}

// ---------------- combine: h = leaky((acc + S@bb)/max(cnt,1) + dprev@root + bias); dL = [h, x] ----
template<int O, int IW>
__global__ void k_combine(const float* __restrict__ acc, const float* __restrict__ S,
                          const float* __restrict__ dprev, const float* __restrict__ bb,
                          const float* __restrict__ root, const float* __restrict__ bias,
                          const float* __restrict__ cntE, const float* __restrict__ x,
                          float* __restrict__ dL) {
    int idx = blockIdx.x * 256 + threadIdx.x;
    int n = idx / O, o = idx % O;
    float sbb = 0.f, rt = 0.f;
    for (int i = 0; i < IW; ++i) {
        sbb = fmaf(S[(size_t)n * IW + i], bb[(size_t)i * O + o], sbb);
        rt  = fmaf(dprev[(size_t)n * IW + i], root[(size_t)i * O + o], rt);
    }
    float c = fmaxf(cntE[n], 1.f);
    float v = (acc[(size_t)n * O + o] + sbb) / c + rt + bias[o];
    v = lrelu(v);
    dL[(size_t)n * (O + F0V) + o] = v;
    if (o < F0V) dL[(size_t)n * (O + F0V) + O + o] = x[n * F0V + o];
}

// ---------------- graph pooling (sum; mean folded into fc1) ----------------
__global__ void k_pool(const float* __restrict__ d3, const int* __restrict__ batch,
                       float* __restrict__ pooled) {
    int idx = blockIdx.x * 256 + threadIdx.x;
    int n = idx / 524, j = idx % 524;
    atomicAdd(&pooled[(size_t)batch[n] * 524 + j], d3[idx]);
}

// ---------------- FC head ----------------
template<int IN, int OUT, bool LEAKY, bool DIV>
__global__ void k_fc(const float* __restrict__ in, const float* __restrict__ W,
                     const float* __restrict__ b, const float* __restrict__ cnt,
                     float* __restrict__ out) {
    int idx = blockIdx.x * blockDim.x + threadIdx.x;
    if (idx >= NG * OUT) return;
    int g = idx / OUT, o = idx % OUT;
    float v = 0.f;
    for (int i = 0; i < IN; ++i) v = fmaf(in[(size_t)g * IN + i], W[(size_t)i * OUT + o], v);
    if (DIV) v /= fmaxf(cnt[g], 1.f);
    v += b[o];
    if (LEAKY) v = lrelu(v);
    out[idx] = v;
}

extern "C" void kernel_launch(void* const* d_in, const int* in_sizes, int n_in,
                              void* d_out, int out_size, void* d_ws, size_t ws_size,
                              hipStream_t stream) {
    const float* x     = (const float*)d_in[0];
    const float* ea    = (const float*)d_in[1];
    const int*   ei    = (const int*)d_in[2];
    const int*   batch = (const int*)d_in[3];
    const float* W1a = (const float*)d_in[4];  const float* b1a = (const float*)d_in[5];
    const float* W1b = (const float*)d_in[6];  const float* b1b = (const float*)d_in[7];
    const float* root1 = (const float*)d_in[8]; const float* bias1 = (const float*)d_in[9];
    const float* W2a = (const float*)d_in[10]; const float* b2a = (const float*)d_in[11];
    const float* W2b = (const float*)d_in[12]; const float* b2b = (const float*)d_in[13];
    const float* root2 = (const float*)d_in[14]; const float* bias2 = (const float*)d_in[15];
    const float* W3a = (const float*)d_in[16]; const float* b3a = (const float*)d_in[17];
    const float* W3b = (const float*)d_in[18]; const float* b3b = (const float*)d_in[19];
    const float* root3 = (const float*)d_in[20]; const float* bias3 = (const float*)d_in[21];
    const float* fc1W = (const float*)d_in[22]; const float* fc1b = (const float*)d_in[23];
    const float* fc2W = (const float*)d_in[24]; const float* fc2b = (const float*)d_in[25];
    const float* fc3W = (const float*)d_in[26]; const float* fc3b = (const float*)d_in[27];
    const int* src = ei;
    const int* dst = ei + EN;
    float* out = (float*)d_out;

    char* wp = (char*)d_ws;
    auto alloc = [&](size_t bytes) { char* p = wp; wp += (bytes + 511) & ~(size_t)511; return p; };
    unsigned* zdup1 = (unsigned*)alloc((size_t)256 * EN * 4);
    unsigned* zdup2 = (unsigned*)alloc((size_t)512 * EN * 4);
    unsigned* zdup3 = (unsigned*)alloc((size_t)512 * EN * 4);
    _Float16* xs1 = (_Float16*)alloc((size_t)EN * 16 * 2);
    _Float16* xs2 = (_Float16*)alloc((size_t)EN * 320 * 2);
    _Float16* xs3 = (_Float16*)alloc((size_t)EN * 320 * 2);
    float* d1 = (float*)alloc((size_t)EN * 268 * 4);
    float* d2 = (float*)alloc((size_t)EN * 268 * 4);
    float* d3 = (float*)alloc((size_t)EN * 524 * 4);
    float* acc = (float*)alloc((size_t)EN * 512 * 4);
    float* S = (float*)alloc((size_t)EN * 268 * 4);
    float* cntE = (float*)alloc((size_t)EN * 4);
    float* cntg = (float*)alloc((size_t)NG * 4);
    float* pooled = (float*)alloc((size_t)NG * 524 * 4);
    float* fc1o = (float*)alloc((size_t)NG * 768 * 4);
    float* fc2o = (float*)alloc((size_t)NG * 1024 * 4);

    // counts (shared across layers)
    hipMemsetAsync(cntE, 0, (size_t)EN * 4, stream);
    hipMemsetAsync(cntg, 0, (size_t)NG * 4, stream);
    k_counts<<<6, 256, 0, stream>>>(dst, batch, cntE, cntg);

    // edge MLPs
    k_edge_mlp<256><<<256 * EN / 256, 256, 0, stream>>>(ea, W1a, b1a, zdup1);
    k_edge_mlp<512><<<512 * EN / 256, 256, 0, stream>>>(ea, W2a, b2a, zdup2);
    k_edge_mlp<512><<<512 * EN / 256, 256, 0, stream>>>(ea, W3a, b3a, zdup3);

    // ---- layer 1 (I=12) ----
    k_gather<16, 12><<<EN * 16 / 256, 256, 0, stream>>>(x, src, xs1);
    hipMemsetAsync(S, 0, (size_t)EN * 12 * 4, stream);
    k_scatter<12><<<EN * 12 / 256, 256, 0, stream>>>(x, src, dst, S);
    hipMemsetAsync(acc, 0, (size_t)EN * 256 * 4, stream);
    edge_gemm<256, 256, 12, 1, 16><<<dim3(6, 1, 43), 512, 0, stream>>>(W1b, zdup1, xs1, dst, acc);
    k_combine<256, 12><<<EN * 256 / 256, 256, 0, stream>>>(acc, S, x, b1b, root1, bias1, cntE, x, d1);

    // ---- layer 2 (I=268, O=256) ----
    k_gather<320, 268><<<EN * 320 / 256, 256, 0, stream>>>(d1, src, xs2);
    hipMemsetAsync(S, 0, (size_t)EN * 268 * 4, stream);
    k_scatter<268><<<EN * 268 / 256, 256, 0, stream>>>(d1, src, dst, S);
    hipMemsetAsync(acc, 0, (size_t)EN * 256 * 4, stream);
    edge_gemm<512, 256, 268, 5, 64><<<dim3(6, 1, 43), 512, 0, stream>>>(W2b, zdup2, xs2, dst, acc);
    k_combine<256, 268><<<EN * 256 / 256, 256, 0, stream>>>(acc, S, d1, b2b, root2, bias2, cntE, x, d2);

    // ---- layer 3 (I=268, O=512) ----
    k_gather<320, 268><<<EN * 320 / 256, 256, 0, stream>>>(d2, src, xs3);
    hipMemsetAsync(S, 0, (size_t)EN * 268 * 4, stream);
    k_scatter<268><<<EN * 268 / 256, 256, 0, stream>>>(d2, src, dst, S);
    hipMemsetAsync(acc, 0, (size_t)EN * 512 * 4, stream);
    edge_gemm<512, 512, 268, 5, 64><<<dim3(6, 2, 22), 512, 0, stream>>>(W3b, zdup3, xs3, dst, acc);
    k_combine<512, 268><<<EN * 512 / 256, 256, 0, stream>>>(acc, S, d2, b3b, root3, bias3, cntE, x, d3);

    // ---- head ----
    hipMemsetAsync(pooled, 0, (size_t)NG * 524 * 4, stream);
    k_pool<<<EN * 524 / 256, 256, 0, stream>>>(d3, batch, pooled);
    k_fc<524, 768, true, true><<<NG * 768 / 256, 256, 0, stream>>>(pooled, fc1W, fc1b, cntg, fc1o);
    k_fc<768, 1024, true, false><<<NG * 1024 / 256, 256, 0, stream>>>(fc1o, fc2W, fc2b, nullptr, fc2o);
    k_fc<1024, 1, false, false><<<1, 64, 0, stream>>>(fc2o, fc3W, fc3b, nullptr, out);
}

// Round 2
// 1432.547 us; speedup vs baseline: 1.2460x; 1.2460x over previous
//
#include <hip/hip_runtime.h>

#define EN 1536     // edges == nodes
#define NG 64
#define F0V 12

typedef _Float16 half8_t __attribute__((ext_vector_type(8)));
typedef float f32x16 __attribute__((ext_vector_type(16)));
typedef unsigned int uint4_t __attribute__((ext_vector_type(4)));

__device__ __forceinline__ float lrelu(float v) { return v >= 0.f ? v : 0.01f * v; }

// ---------------- counts: edges per dst node, nodes per graph ----------------
__global__ void k_counts(const int* __restrict__ dst, const int* __restrict__ batch,
                         float* __restrict__ cntE, float* __restrict__ cntg) {
    int t = blockIdx.x * 256 + threadIdx.x;
    if (t < EN) {
        atomicAdd(&cntE[dst[t]], 1.f);
        atomicAdd(&cntg[batch[t]], 1.f);
    }
}

// ---------------- edge MLP first layer: z = leaky(ea@Wa+ba), dup-packed f16 [K][E] ----
template<int K>
__global__ void k_edge_mlp(const float* __restrict__ ea, const float* __restrict__ Wa,
                           const float* __restrict__ ba, unsigned* __restrict__ zdup) {
    int idx = blockIdx.x * 256 + threadIdx.x;
    int e = idx % EN, k = idx / EN;
    if (k >= K) return;
    float u = ba[k];
#pragma unroll
    for (int a = 0; a < 4; ++a) u += ea[e * 4 + a] * Wa[a * K + k];
    u = lrelu(u);
    _Float16 h = (_Float16)u;
    unsigned short us = __builtin_bit_cast(unsigned short, h);
    zdup[(size_t)k * EN + e] = (unsigned)us * 0x10001u;
}

// ---------------- gather src features to f16 in MFMA A-fragment order ----------------
// element layout: chunk cg = (mt*NIQ+iq)*NI0*8 + i0*8 + eg ; within chunk: lane*8+j
// value = feat[src[mt*256 + eg*32 + (lane&31)]][iq*IC + i0*16 + (lane>>5)*8 + j]
template<int NIQ, int IC, int IACT>
__global__ void k_gatherw(const float* __restrict__ feat, const int* __restrict__ src,
                          _Float16* __restrict__ xsw) {
    constexpr int NI0 = IC / 16;
    int idx = blockIdx.x * 256 + threadIdx.x;
    int pc = idx & 511, cg = idx >> 9;
    int lane = pc >> 3, j = pc & 7;
    int c2 = cg % (NI0 * 8), tq = cg / (NI0 * 8);
    int iq = tq % NIQ, mt = tq / NIQ;
    int i0 = c2 >> 3, eg = c2 & 7;
    int e = mt * 256 + eg * 32 + (lane & 31);
    int i = iq * IC + i0 * 16 + (lane >> 5) * 8 + j;
    float v = (i < IACT) ? feat[(size_t)src[e] * IACT + i] : 0.f;
    xsw[idx] = (_Float16)v;
}

// ---------------- pre-swizzle Wb -> f16 tiles in B-fragment LDS order ----------------
// Bs tile (by = nt*NIQ+iq, k): IC x 256, chunk c = i0*8+g, pos lane*8+j:
//   value Wb[k][iq*IC + i0*16 + (lane>>5)*8 + j][nt*256 + g*32 + (lane&31)]
template<int O, int IACT, int NIQ, int IC>
__global__ void k_swz(const float* __restrict__ Wb, _Float16* __restrict__ Bs) {
    const int k = blockIdx.x, KT = gridDim.x;
    const int nt = blockIdx.y / NIQ, iq = blockIdx.y % NIQ;
    __shared__ float tile[IC * 258];
    const int t = threadIdx.x;
#pragma unroll
    for (int u = 0; u < IC / 8; ++u) {
        int r = u * 8 + (t >> 6), c4 = t & 63;
        int i = iq * IC + r;
        float4 v = {0.f, 0.f, 0.f, 0.f};
        if (i < IACT) v = *(const float4*)(Wb + ((size_t)k * IACT + i) * O + nt * 256 + c4 * 4);
        tile[r * 258 + c4 * 4 + 0] = v.x;
        tile[r * 258 + c4 * 4 + 1] = v.y;
        tile[r * 258 + c4 * 4 + 2] = v.z;
        tile[r * 258 + c4 * 4 + 3] = v.w;
    }
    __syncthreads();
    constexpr int PT = IC * 256 / 512;
    _Float16 ov[PT];
#pragma unroll
    for (int q = 0; q < PT; ++q) {
        int p = t * PT + q;
        int c = p >> 9, pc = p & 511, ln = pc >> 3, j = pc & 7;
        int i0 = c >> 3, g = c & 7;
        int il = i0 * 16 + (ln >> 5) * 8 + j;
        int nl = g * 32 + (ln & 31);
        ov[q] = (_Float16)tile[il * 258 + nl];
    }
    size_t base = ((size_t)blockIdx.y * KT + k) * (size_t)(IC * 256) + (size_t)t * PT;
#pragma unroll
    for (int q8 = 0; q8 < PT / 8; ++q8)
        *(half8_t*)(Bs + base + q8 * 8) = *(const half8_t*)(ov + q8 * 8);
}

// ---------------- scatter-add gathered features by dst ----------------
template<int IW>
__global__ void k_scatter(const float* __restrict__ feat, const int* __restrict__ src,
                          const int* __restrict__ dst, float* __restrict__ S) {
    int idx = blockIdx.x * 256 + threadIdx.x;
    int e = idx / IW, i = idx % IW;
    atomicAdd(&S[(size_t)dst[e] * IW + i], feat[(size_t)src[e] * IW + i]);
}

// ---------------- fused edge-message GEMM (m97-style async K-loop) ----------------
template<int KTOT, int O, int NIQ, int IC, int ZMAX>
__global__ __launch_bounds__(512, 2)
void edge_gemm(const _Float16* __restrict__ Bs, const unsigned* __restrict__ zdup,
               const _Float16* __restrict__ xsw, const int* __restrict__ dstIdx,
               float* __restrict__ accG) {
    constexpr int NI0 = IC / 16;
    constexpr int TILEH = IC * 256;       // halfs per B tile
    constexpr int CPW = (TILEH / 512) / 8;  // DMA chunks per wave

    __shared__ __attribute__((aligned(16))) _Float16 BL[2][TILEH];
    __shared__ unsigned zL[ZMAX * 256];
    __shared__ int dstL[256];

    const int t = threadIdx.x, lane = t & 63, w = t >> 6;
    const int wm = w >> 1, wn = w & 1;    // 4 m-waves x 2 n-waves
    const int mt = blockIdx.x, nt = blockIdx.y, zb = blockIdx.z, NZ = gridDim.z;
    const int e0 = mt * 256, n0 = nt * 256;
    const int k0 = (KTOT * zb) / NZ, k1 = (KTOT * (zb + 1)) / NZ, kn = k1 - k0;

    if (t < 256) dstL[t] = dstIdx[e0 + t];
    for (int idx = t; idx < kn * 256; idx += 512)
        zL[idx] = zdup[(size_t)(k0 + (idx >> 8)) * EN + e0 + (idx & 255)];

    f32x16 acc[2][4] = {};
    const _Float16* xbase = xsw + (size_t)mt * NIQ * NI0 * 8 * 512;
    half8_t xsr[NI0][2];

    auto dma_issue = [&](const _Float16* srcp, int buf) {
#pragma unroll
        for (int u = 0; u < CPW; ++u) {
            int ch = w * CPW + u;
            __builtin_amdgcn_global_load_lds(
                (__attribute__((address_space(1))) void*)(srcp + ch * 512 + lane * 8),
                (__attribute__((address_space(3))) void*)(&BL[buf][ch * 512]),
                16, 0, 0);
        }
    };

    const _Float16* pB = Bs + ((size_t)(nt * NIQ) * KTOT + k0) * TILEH;
    int kk_n = 0;
    auto adv = [&]() {
        if (++kk_n == kn) { kk_n = 0; pB += (size_t)(KTOT - kn + 1) * TILEH; }
        else pB += (size_t)TILEH;
    };

    const int S = NIQ * kn;
    dma_issue(pB, 0);
    adv();

    int iq = 0, kk = 0;
    for (int s = 0; s < S; ++s) {
        const int buf = s & 1;
        __syncthreads();                       // drains DMA for buf, fences BL reuse
        if (s + 1 < S) { dma_issue(pB, buf ^ 1); adv(); }
        if (kk == 0) {                         // new iq chunk: reload xs fragments
#pragma unroll
            for (int i0 = 0; i0 < NI0; ++i0)
#pragma unroll
                for (int mf = 0; mf < 2; ++mf)
                    xsr[i0][mf] = *(const half8_t*)(xbase +
                        ((size_t)iq * NI0 * 8 + i0 * 8 + wm * 2 + mf) * 512 + lane * 8);
        }
        unsigned zd0 = zL[kk * 256 + wm * 64 + (lane & 31)];
        unsigned zd1 = zL[kk * 256 + wm * 64 + 32 + (lane & 31)];
        uint4_t u0 = {zd0, zd0, zd0, zd0}, u1 = {zd1, zd1, zd1, zd1};
        half8_t z0 = __builtin_bit_cast(half8_t, u0);
        half8_t z1 = __builtin_bit_cast(half8_t, u1);
#pragma unroll
        for (int i0 = 0; i0 < NI0; ++i0) {
            half8_t a0 = xsr[i0][0] * z0;
            half8_t a1 = xsr[i0][1] * z1;
#pragma unroll
            for (int nf = 0; nf < 4; ++nf) {
                half8_t b = *(const half8_t*)(&BL[buf][(i0 * 8 + wn * 4 + nf) * 512 + lane * 8]);
                acc[0][nf] = __builtin_amdgcn_mfma_f32_32x32x16_f16(a0, b, acc[0][nf], 0, 0, 0);
                acc[1][nf] = __builtin_amdgcn_mfma_f32_32x32x16_f16(a1, b, acc[1][nf], 0, 0, 0);
            }
        }
        if (++kk == kn) { kk = 0; ++iq; }
    }

    // epilogue: fused segment-sum scatter (32x32 C layout: col=lane&31, row=(r&3)+8*(r>>2)+4*(lane>>5))
#pragma unroll
    for (int mf = 0; mf < 2; ++mf)
#pragma unroll
        for (int nf = 0; nf < 4; ++nf)
#pragma unroll
            for (int r = 0; r < 16; ++r) {
                int row = (r & 3) + 8 * (r >> 2) + 4 * (lane >> 5);
                int m = wm * 64 + mf * 32 + row;
                int o = wn * 128 + nf * 32 + (lane & 31);
                atomicAdd(&accG[(size_t)dstL[m] * O + n0 + o], acc[mf][nf][r]);
            }
}

// ---------------- combine: h = leaky((acc + S@bb)/max(cnt,1) + dprev@root + bias); dL=[h,x] ----
template<int O, int IW>
__global__ void k_combine(const float* __restrict__ acc, const float* __restrict__ S,
                          const float* __restrict__ dprev, const float* __restrict__ bb,
                          const float* __restrict__ root, const float* __restrict__ bias,
                          const float* __restrict__ cntE, const float* __restrict__ x,
                          float* __restrict__ dL) {
    int idx = blockIdx.x * 256 + threadIdx.x;
    int n = idx / O, o = idx % O;
    float sbb = 0.f, rt = 0.f;
    for (int i = 0; i < IW; ++i) {
        sbb = fmaf(S[(size_t)n * IW + i], bb[(size_t)i * O + o], sbb);
        rt  = fmaf(dprev[(size_t)n * IW + i], root[(size_t)i * O + o], rt);
    }
    float c = fmaxf(cntE[n], 1.f);
    float v = (acc[(size_t)n * O + o] + sbb) / c + rt + bias[o];
    v = lrelu(v);
    dL[(size_t)n * (O + F0V) + o] = v;
    if (o < F0V) dL[(size_t)n * (O + F0V) + O + o] = x[n * F0V + o];
}

// ---------------- graph pooling (sum; mean folded into fc1) ----------------
__global__ void k_pool(const float* __restrict__ d3, const int* __restrict__ batch,
                       float* __restrict__ pooled) {
    int idx = blockIdx.x * 256 + threadIdx.x;
    int n = idx / 524, j = idx % 524;
    atomicAdd(&pooled[(size_t)batch[n] * 524 + j], d3[idx]);
}

// ---------------- FC head (g = lane -> W loads are wave-uniform/scalarized) ----------------
template<int IN, int OUT, bool LEAKY, bool DIV>
__global__ void k_fc(const float* __restrict__ in, const float* __restrict__ W,
                     const float* __restrict__ b, const float* __restrict__ cnt,
                     float* __restrict__ out) {
    int idx = blockIdx.x * blockDim.x + threadIdx.x;
    if (idx >= NG * OUT) return;
    int g = idx & 63, o = idx >> 6;
    float v = 0.f;
    for (int i = 0; i < IN; ++i) v = fmaf(in[(size_t)g * IN + i], W[(size_t)i * OUT + o], v);
    if (DIV) v /= fmaxf(cnt[g], 1.f);
    v += b[o];
    if (LEAKY) v = lrelu(v);
    out[(size_t)g * OUT + o] = v;
}

extern "C" void kernel_launch(void* const* d_in, const int* in_sizes, int n_in,
                              void* d_out, int out_size, void* d_ws, size_t ws_size,
                              hipStream_t stream) {
    const float* x     = (const float*)d_in[0];
    const float* ea    = (const float*)d_in[1];
    const int*   ei    = (const int*)d_in[2];
    const int*   batch = (const int*)d_in[3];
    const float* W1a = (const float*)d_in[4];  const float* b1a = (const float*)d_in[5];
    const float* W1b = (const float*)d_in[6];  const float* b1b = (const float*)d_in[7];
    const float* root1 = (const float*)d_in[8]; const float* bias1 = (const float*)d_in[9];
    const float* W2a = (const float*)d_in[10]; const float* b2a = (const float*)d_in[11];
    const float* W2b = (const float*)d_in[12]; const float* b2b = (const float*)d_in[13];
    const float* root2 = (const float*)d_in[14]; const float* bias2 = (const float*)d_in[15];
    const float* W3a = (const float*)d_in[16]; const float* b3a = (const float*)d_in[17];
    const float* W3b = (const float*)d_in[18]; const float* b3b = (const float*)d_in[19];
    const float* root3 = (const float*)d_in[20]; const float* bias3 = (const float*)d_in[21];
    const float* fc1W = (const float*)d_in[22]; const float* fc1b = (const float*)d_in[23];
    const float* fc2W = (const float*)d_in[24]; const float* fc2b = (const float*)d_in[25];
    const float* fc3W = (const float*)d_in[26]; const float* fc3b = (const float*)d_in[27];
    const int* src = ei;
    const int* dst = ei + EN;
    float* out = (float*)d_out;

    char* wp = (char*)d_ws;
    auto alloc = [&](size_t bytes) { char* p = wp; wp += (bytes + 511) & ~(size_t)511; return p; };
    unsigned* zdup1 = (unsigned*)alloc((size_t)256 * EN * 4);
    unsigned* zdup2 = (unsigned*)alloc((size_t)512 * EN * 4);
    unsigned* zdup3 = (unsigned*)alloc((size_t)512 * EN * 4);
    _Float16* xsw1 = (_Float16*)alloc((size_t)EN * 16 * 2);
    _Float16* xsw2 = (_Float16*)alloc((size_t)EN * 320 * 2);
    _Float16* xsw3 = (_Float16*)alloc((size_t)EN * 320 * 2);
    // single Bs buffer, reused per layer (layer3 is biggest: 10*512*16384 halfs = 168 MB)
    _Float16* Bs = (_Float16*)alloc((size_t)10 * 512 * 16384 * 2);
    float* d1 = (float*)alloc((size_t)EN * 268 * 4);
    float* d2 = (float*)alloc((size_t)EN * 268 * 4);
    float* d3 = (float*)alloc((size_t)EN * 524 * 4);
    float* acc = (float*)alloc((size_t)EN * 512 * 4);
    float* S = (float*)alloc((size_t)EN * 268 * 4);
    float* cntE = (float*)alloc((size_t)EN * 4);
    float* cntg = (float*)alloc((size_t)NG * 4);
    float* pooled = (float*)alloc((size_t)NG * 524 * 4);
    float* fc1o = (float*)alloc((size_t)NG * 768 * 4);
    float* fc2o = (float*)alloc((size_t)NG * 1024 * 4);

    // counts (shared across layers)
    hipMemsetAsync(cntE, 0, (size_t)EN * 4, stream);
    hipMemsetAsync(cntg, 0, (size_t)NG * 4, stream);
    k_counts<<<6, 256, 0, stream>>>(dst, batch, cntE, cntg);

    // edge MLPs
    k_edge_mlp<256><<<256 * EN / 256, 256, 0, stream>>>(ea, W1a, b1a, zdup1);
    k_edge_mlp<512><<<512 * EN / 256, 256, 0, stream>>>(ea, W2a, b2a, zdup2);
    k_edge_mlp<512><<<512 * EN / 256, 256, 0, stream>>>(ea, W3a, b3a, zdup3);

    // ---- layer 1 (I=12 -> pad 16, O=256) ----
    k_gatherw<1, 16, 12><<<EN * 16 / 256, 256, 0, stream>>>(x, src, xsw1);
    k_swz<256, 12, 1, 16><<<dim3(256, 1), 512, 0, stream>>>(W1b, Bs);
    hipMemsetAsync(S, 0, (size_t)EN * 12 * 4, stream);
    k_scatter<12><<<EN * 12 / 256, 256, 0, stream>>>(x, src, dst, S);
    hipMemsetAsync(acc, 0, (size_t)EN * 256 * 4, stream);
    edge_gemm<256, 256, 1, 16, 8><<<dim3(6, 1, 42), 512, 0, stream>>>(Bs, zdup1, xsw1, dst, acc);
    k_combine<256, 12><<<EN * 256 / 256, 256, 0, stream>>>(acc, S, x, b1b, root1, bias1, cntE, x, d1);

    // ---- layer 2 (I=268 -> pad 320, O=256) ----
    k_gatherw<5, 64, 268><<<EN * 320 / 256, 256, 0, stream>>>(d1, src, xsw2);
    k_swz<256, 268, 5, 64><<<dim3(512, 5), 512, 0, stream>>>(W2b, Bs);
    hipMemsetAsync(S, 0, (size_t)EN * 268 * 4, stream);
    k_scatter<268><<<EN * 268 / 256, 256, 0, stream>>>(d1, src, dst, S);
    hipMemsetAsync(acc, 0, (size_t)EN * 256 * 4, stream);
    edge_gemm<512, 256, 5, 64, 14><<<dim3(6, 1, 42), 512, 0, stream>>>(Bs, zdup2, xsw2, dst, acc);
    k_combine<256, 268><<<EN * 256 / 256, 256, 0, stream>>>(acc, S, d1, b2b, root2, bias2, cntE, x, d2);

    // ---- layer 3 (I=268 -> pad 320, O=512) ----
    k_gatherw<5, 64, 268><<<EN * 320 / 256, 256, 0, stream>>>(d2, src, xsw3);
    k_swz<512, 268, 5, 64><<<dim3(512, 10), 512, 0, stream>>>(W3b, Bs);
    hipMemsetAsync(S, 0, (size_t)EN * 268 * 4, stream);
    k_scatter<268><<<EN * 268 / 256, 256, 0, stream>>>(d2, src, dst, S);
    hipMemsetAsync(acc, 0, (size_t)EN * 512 * 4, stream);
    edge_gemm<512, 512, 5, 64, 26><<<dim3(6, 2, 21), 512, 0, stream>>>(Bs, zdup3, xsw3, dst, acc);
    k_combine<512, 268><<<EN * 512 / 256, 256, 0, stream>>>(acc, S, d2, b3b, root3, bias3, cntE, x, d3);

    // ---- head ----
    hipMemsetAsync(pooled, 0, (size_t)NG * 524 * 4, stream);
    k_pool<<<EN * 524 / 256, 256, 0, stream>>>(d3, batch, pooled);
    k_fc<524, 768, true, true><<<NG * 768 / 256, 256, 0, stream>>>(pooled, fc1W, fc1b, cntg, fc1o);
    k_fc<768, 1024, true, false><<<NG * 1024 / 256, 256, 0, stream>>>(fc1o, fc2W, fc2b, nullptr, fc2o);
    k_fc<1024, 1, false, false><<<1, 64, 0, stream>>>(fc2o, fc3W, fc3b, nullptr, out);
}

// Round 3
// 1337.195 us; speedup vs baseline: 1.3349x; 1.0713x over previous
//
#include <hip/hip_runtime.h>

#define EN 1536     // edges == nodes
#define NG 64
#define F0V 12

typedef _Float16 half8_t __attribute__((ext_vector_type(8)));
typedef float f32x16 __attribute__((ext_vector_type(16)));
typedef unsigned int uint4_t __attribute__((ext_vector_type(4)));

__device__ __forceinline__ float lrelu(float v) { return v >= 0.f ? v : 0.01f * v; }

// ---------------- counts: edges per dst node, nodes per graph ----------------
__global__ void k_counts(const int* __restrict__ dst, const int* __restrict__ batch,
                         float* __restrict__ cntE, float* __restrict__ cntg) {
    int t = blockIdx.x * 256 + threadIdx.x;
    if (t < EN) {
        atomicAdd(&cntE[dst[t]], 1.f);
        atomicAdd(&cntg[batch[t]], 1.f);
    }
}

// ---------------- edge MLP first layer: z = leaky(ea@Wa+ba), dup-packed f16 [K][E] ----
template<int K>
__global__ void k_edge_mlp(const float* __restrict__ ea, const float* __restrict__ Wa,
                           const float* __restrict__ ba, unsigned* __restrict__ zdup) {
    int idx = blockIdx.x * 256 + threadIdx.x;
    int e = idx % EN, k = idx / EN;
    if (k >= K) return;
    float u = ba[k];
#pragma unroll
    for (int a = 0; a < 4; ++a) u += ea[e * 4 + a] * Wa[a * K + k];
    u = lrelu(u);
    _Float16 h = (_Float16)u;
    unsigned short us = __builtin_bit_cast(unsigned short, h);
    zdup[(size_t)k * EN + e] = (unsigned)us * 0x10001u;
}

// ---------------- gather src features to f16 in MFMA A-fragment order + fused dst scatter ----
// chunk cg = (mt*NIQ+iq)*NI0*8 + i0*8 + eg ; within chunk lane*8+j
// value = feat[src[mt*256 + eg*32 + (lane&31)]][iq*IC + i0*16 + (lane>>5)*8 + j]
template<int NIQ, int IC, int IACT>
__global__ void k_gatherw(const float* __restrict__ feat, const int* __restrict__ src,
                          const int* __restrict__ dst, _Float16* __restrict__ xsw,
                          float* __restrict__ S) {
    constexpr int NI0 = IC / 16;
    int idx = blockIdx.x * 256 + threadIdx.x;
    int pc = idx & 511, cg = idx >> 9;
    int lane = pc >> 3, j = pc & 7;
    int c2 = cg % (NI0 * 8), tq = cg / (NI0 * 8);
    int iq = tq % NIQ, mt = tq / NIQ;
    int i0 = c2 >> 3, eg = c2 & 7;
    int e = mt * 256 + eg * 32 + (lane & 31);
    int i = iq * IC + i0 * 16 + (lane >> 5) * 8 + j;
    float v = 0.f;
    if (i < IACT) {
        v = feat[(size_t)src[e] * IACT + i];
        atomicAdd(&S[(size_t)dst[e] * IACT + i], v);   // fused segment-sum of gathered feats
    }
    xsw[idx] = (_Float16)v;
}

// ---------------- pre-swizzle Wb -> f16 tiles in B-fragment LDS order ----------------
// tile (by = nt*NIQ+iq, k): IC x 128 halfs; chunk c = i0*4+g, pos lane*8+j:
//   value Wb[k][iq*IC + i0*16 + (lane>>5)*8 + j][nt*128 + g*32 + (lane&31)]
template<int O, int IACT, int NIQ, int IC>
__global__ void k_swz(const float* __restrict__ Wb, _Float16* __restrict__ Bs) {
    const int k = blockIdx.x, KT = gridDim.x;
    const int nt = blockIdx.y / NIQ, iq = blockIdx.y % NIQ;
    __shared__ float tile[IC * 132];
    const int t = threadIdx.x;
#pragma unroll
    for (int u = 0; u < IC / 8; ++u) {
        int r = u * 8 + (t >> 5), c4 = t & 31;
        int i = iq * IC + r;
        float4 v = {0.f, 0.f, 0.f, 0.f};
        if (i < IACT) v = *(const float4*)(Wb + ((size_t)k * IACT + i) * O + nt * 128 + c4 * 4);
        tile[r * 132 + c4 * 4 + 0] = v.x;
        tile[r * 132 + c4 * 4 + 1] = v.y;
        tile[r * 132 + c4 * 4 + 2] = v.z;
        tile[r * 132 + c4 * 4 + 3] = v.w;
    }
    __syncthreads();
    constexpr int PT = IC * 128 / 256;
    _Float16 ov[PT];
#pragma unroll
    for (int q = 0; q < PT; ++q) {
        int p = t * PT + q;
        int c = p >> 9, pc = p & 511, ln = pc >> 3, j = pc & 7;
        int i0 = c >> 2, g = c & 3;
        int il = i0 * 16 + (ln >> 5) * 8 + j;
        int nl = g * 32 + (ln & 31);
        ov[q] = (_Float16)tile[il * 132 + nl];
    }
    size_t base = ((size_t)blockIdx.y * KT + k) * (size_t)(IC * 128) + (size_t)t * PT;
#pragma unroll
    for (int q8 = 0; q8 < PT / 8; ++q8)
        *(half8_t*)(Bs + base + q8 * 8) = *(const half8_t*)(ov + q8 * 8);
}

// ---------------- fused edge-message GEMM: 256 thr (4 m-waves), tile 256x128, 2 blocks/CU ----
template<int KTOT, int O, int NIQ, int IC, int ZMAX>
__global__ __launch_bounds__(256, 2)
void edge_gemm(const _Float16* __restrict__ Bs, const unsigned* __restrict__ zdup,
               const _Float16* __restrict__ xsw, const int* __restrict__ dstIdx,
               float* __restrict__ accG) {
    constexpr int NI0 = IC / 16;
    constexpr int TILEH = IC * 128;        // halfs per B tile
    constexpr int CPW = NI0;               // DMA chunks (512h) per wave

    __shared__ __attribute__((aligned(16))) _Float16 BL[2][TILEH];
    __shared__ unsigned zL[ZMAX * 256];
    __shared__ int dstL[256];

    const int t = threadIdx.x, lane = t & 63, wm = t >> 6;   // 4 m-waves
    const int mt = blockIdx.x, nt = blockIdx.y, zb = blockIdx.z, NZ = gridDim.z;
    const int e0 = mt * 256, n0 = nt * 128;
    const int k0 = (KTOT * zb) / NZ, k1 = (KTOT * (zb + 1)) / NZ, kn = k1 - k0;

    dstL[t] = dstIdx[e0 + t];
    for (int idx = t; idx < kn * 256; idx += 256)
        zL[idx] = zdup[(size_t)(k0 + (idx >> 8)) * EN + e0 + (idx & 255)];

    f32x16 acc[2][4] = {};
    const _Float16* xbase = xsw + (size_t)mt * NIQ * NI0 * 8 * 512;
    half8_t xsr[NI0][2];

    auto dma_issue = [&](const _Float16* srcp, int buf) {
#pragma unroll
        for (int u = 0; u < CPW; ++u) {
            int ch = wm * CPW + u;
            __builtin_amdgcn_global_load_lds(
                (__attribute__((address_space(1))) void*)(srcp + ch * 512 + lane * 8),
                (__attribute__((address_space(3))) void*)(&BL[buf][ch * 512]),
                16, 0, 0);
        }
    };

    const _Float16* pB = Bs + ((size_t)(nt * NIQ) * KTOT + k0) * TILEH;
    int kk_n = 0;
    auto adv = [&]() {
        if (++kk_n == kn) { kk_n = 0; pB += (size_t)(KTOT - kn + 1) * TILEH; }
        else pB += (size_t)TILEH;
    };

    const int S = NIQ * kn;
    dma_issue(pB, 0);
    adv();

    int iq = 0, kk = 0;
    for (int s = 0; s < S; ++s) {
        const int buf = s & 1;
        __syncthreads();                       // drains DMA for buf, fences BL reuse
        if (s + 1 < S) { dma_issue(pB, buf ^ 1); adv(); }
        if (kk == 0) {                         // new iq chunk: reload xs fragments
#pragma unroll
            for (int i0 = 0; i0 < NI0; ++i0)
#pragma unroll
                for (int mf = 0; mf < 2; ++mf)
                    xsr[i0][mf] = *(const half8_t*)(xbase +
                        ((size_t)(iq * NI0 + i0) * 8 + wm * 2 + mf) * 512 + lane * 8);
        }
        unsigned zd0 = zL[kk * 256 + wm * 64 + (lane & 31)];
        unsigned zd1 = zL[kk * 256 + wm * 64 + 32 + (lane & 31)];
        uint4_t u0 = {zd0, zd0, zd0, zd0}, u1 = {zd1, zd1, zd1, zd1};
        half8_t z0 = __builtin_bit_cast(half8_t, u0);
        half8_t z1 = __builtin_bit_cast(half8_t, u1);
#pragma unroll
        for (int i0 = 0; i0 < NI0; ++i0) {
            half8_t a0 = xsr[i0][0] * z0;
            half8_t a1 = xsr[i0][1] * z1;
#pragma unroll
            for (int nf = 0; nf < 4; ++nf) {
                half8_t b = *(const half8_t*)(&BL[buf][(i0 * 4 + nf) * 512 + lane * 8]);
                acc[0][nf] = __builtin_amdgcn_mfma_f32_32x32x16_f16(a0, b, acc[0][nf], 0, 0, 0);
                acc[1][nf] = __builtin_amdgcn_mfma_f32_32x32x16_f16(a1, b, acc[1][nf], 0, 0, 0);
            }
        }
        if (++kk == kn) { kk = 0; ++iq; }
    }

    // epilogue: fused segment-sum scatter (32x32 C layout: col=lane&31, row=(r&3)+8*(r>>2)+4*(lane>>5))
#pragma unroll
    for (int mf = 0; mf < 2; ++mf)
#pragma unroll
        for (int nf = 0; nf < 4; ++nf)
#pragma unroll
            for (int r = 0; r < 16; ++r) {
                int row = (r & 3) + 8 * (r >> 2) + 4 * (lane >> 5);
                int m = wm * 64 + mf * 32 + row;
                int o = nf * 32 + (lane & 31);
                atomicAdd(&accG[(size_t)dstL[m] * O + n0 + o], acc[mf][nf][r]);
            }
}

// ---------------- combine: h = leaky((acc + S@bb)/max(cnt,1) + dprev@root + bias); dL=[h,x] ----
template<int O, int IW>
__global__ void k_combine(const float* __restrict__ acc, const float* __restrict__ S,
                          const float* __restrict__ dprev, const float* __restrict__ bb,
                          const float* __restrict__ root, const float* __restrict__ bias,
                          const float* __restrict__ cntE, const float* __restrict__ x,
                          float* __restrict__ dL) {
    int idx = blockIdx.x * 256 + threadIdx.x;
    int n = idx / O, o = idx % O;
    float sbb = 0.f, rt = 0.f;
    for (int i = 0; i < IW; ++i) {
        sbb = fmaf(S[(size_t)n * IW + i], bb[(size_t)i * O + o], sbb);
        rt  = fmaf(dprev[(size_t)n * IW + i], root[(size_t)i * O + o], rt);
    }
    float c = fmaxf(cntE[n], 1.f);
    float v = (acc[(size_t)n * O + o] + sbb) / c + rt + bias[o];
    v = lrelu(v);
    dL[(size_t)n * (O + F0V) + o] = v;
    if (o < F0V) dL[(size_t)n * (O + F0V) + O + o] = x[n * F0V + o];
}

// ---------------- graph pooling (sum; mean folded into fc1) ----------------
__global__ void k_pool(const float* __restrict__ d3, const int* __restrict__ batch,
                       float* __restrict__ pooled) {
    int idx = blockIdx.x * 256 + threadIdx.x;
    int n = idx / 524, j = idx % 524;
    atomicAdd(&pooled[(size_t)batch[n] * 524 + j], d3[idx]);
}

// ---------------- FC head (g = lane -> W loads are wave-uniform/scalarized) ----------------
template<int IN, int OUT, bool LEAKY, bool DIV>
__global__ void k_fc(const float* __restrict__ in, const float* __restrict__ W,
                     const float* __restrict__ b, const float* __restrict__ cnt,
                     float* __restrict__ out) {
    int idx = blockIdx.x * blockDim.x + threadIdx.x;
    if (idx >= NG * OUT) return;
    int g = idx & 63, o = idx >> 6;
    float v = 0.f;
    for (int i = 0; i < IN; ++i) v = fmaf(in[(size_t)g * IN + i], W[(size_t)i * OUT + o], v);
    if (DIV) v /= fmaxf(cnt[g], 1.f);
    v += b[o];
    if (LEAKY) v = lrelu(v);
    out[(size_t)g * OUT + o] = v;
}

// ---------------- fc3: one block per graph, parallel reduction ----------------
__global__ void k_fc3r(const float* __restrict__ in, const float* __restrict__ W,
                       const float* __restrict__ b, float* __restrict__ out) {
    __shared__ float red[256];
    int g = blockIdx.x, t = threadIdx.x;
    float v = 0.f;
    for (int i = t; i < 1024; i += 256) v = fmaf(in[(size_t)g * 1024 + i], W[i], v);
    red[t] = v;
    __syncthreads();
    for (int s = 128; s > 0; s >>= 1) {
        if (t < s) red[t] += red[t + s];
        __syncthreads();
    }
    if (t == 0) out[g] = red[0] + b[0];
}

extern "C" void kernel_launch(void* const* d_in, const int* in_sizes, int n_in,
                              void* d_out, int out_size, void* d_ws, size_t ws_size,
                              hipStream_t stream) {
    const float* x     = (const float*)d_in[0];
    const float* ea    = (const float*)d_in[1];
    const int*   ei    = (const int*)d_in[2];
    const int*   batch = (const int*)d_in[3];
    const float* W1a = (const float*)d_in[4];  const float* b1a = (const float*)d_in[5];
    const float* W1b = (const float*)d_in[6];  const float* b1b = (const float*)d_in[7];
    const float* root1 = (const float*)d_in[8]; const float* bias1 = (const float*)d_in[9];
    const float* W2a = (const float*)d_in[10]; const float* b2a = (const float*)d_in[11];
    const float* W2b = (const float*)d_in[12]; const float* b2b = (const float*)d_in[13];
    const float* root2 = (const float*)d_in[14]; const float* bias2 = (const float*)d_in[15];
    const float* W3a = (const float*)d_in[16]; const float* b3a = (const float*)d_in[17];
    const float* W3b = (const float*)d_in[18]; const float* b3b = (const float*)d_in[19];
    const float* root3 = (const float*)d_in[20]; const float* bias3 = (const float*)d_in[21];
    const float* fc1W = (const float*)d_in[22]; const float* fc1b = (const float*)d_in[23];
    const float* fc2W = (const float*)d_in[24]; const float* fc2b = (const float*)d_in[25];
    const float* fc3W = (const float*)d_in[26]; const float* fc3b = (const float*)d_in[27];
    const int* src = ei;
    const int* dst = ei + EN;
    float* out = (float*)d_out;

    char* wp = (char*)d_ws;
    auto alloc = [&](size_t bytes) { char* p = wp; wp += (bytes + 511) & ~(size_t)511; return p; };
    unsigned* zdup1 = (unsigned*)alloc((size_t)256 * EN * 4);
    unsigned* zdup2 = (unsigned*)alloc((size_t)512 * EN * 4);
    unsigned* zdup3 = (unsigned*)alloc((size_t)512 * EN * 4);
    _Float16* xsw1 = (_Float16*)alloc((size_t)EN * 16 * 2);
    _Float16* xsw2 = (_Float16*)alloc((size_t)EN * 288 * 2);
    _Float16* xsw3 = (_Float16*)alloc((size_t)EN * 288 * 2);
    // Bs reused per layer (layer3 biggest: (512/128)*9*512 tiles * 4096 halfs = 151 MB)
    _Float16* Bs = (_Float16*)alloc((size_t)4 * 9 * 512 * 4096 * 2);
    float* d1 = (float*)alloc((size_t)EN * 268 * 4);
    float* d2 = (float*)alloc((size_t)EN * 268 * 4);
    float* d3 = (float*)alloc((size_t)EN * 524 * 4);
    float* acc = (float*)alloc((size_t)EN * 512 * 4);
    float* S = (float*)alloc((size_t)EN * 268 * 4);   // adjacent to acc: single memset covers both
    float* cntE = (float*)alloc((size_t)EN * 4);
    float* cntg = (float*)alloc((size_t)NG * 4);       // adjacent to cntE
    float* pooled = (float*)alloc((size_t)NG * 524 * 4);
    float* fc1o = (float*)alloc((size_t)NG * 768 * 4);
    float* fc2o = (float*)alloc((size_t)NG * 1024 * 4);
    const size_t accS_bytes = ((size_t)EN * 512 * 4 + 511 & ~(size_t)511) + (size_t)EN * 268 * 4;

    // counts (shared across layers)
    hipMemsetAsync(cntE, 0, ((size_t)EN * 4 + 511 & ~(size_t)511) + NG * 4, stream);
    k_counts<<<6, 256, 0, stream>>>(dst, batch, cntE, cntg);

    // edge MLPs
    k_edge_mlp<256><<<256 * EN / 256, 256, 0, stream>>>(ea, W1a, b1a, zdup1);
    k_edge_mlp<512><<<512 * EN / 256, 256, 0, stream>>>(ea, W2a, b2a, zdup2);
    k_edge_mlp<512><<<512 * EN / 256, 256, 0, stream>>>(ea, W3a, b3a, zdup3);

    // ---- layer 1 (I=12 -> pad 16, O=256) ----
    hipMemsetAsync(acc, 0, accS_bytes, stream);
    k_gatherw<1, 16, 12><<<EN * 16 / 256, 256, 0, stream>>>(x, src, dst, xsw1, S);
    k_swz<256, 12, 1, 16><<<dim3(256, 2), 256, 0, stream>>>(W1b, Bs);
    edge_gemm<256, 256, 1, 16, 7><<<dim3(6, 2, 42), 256, 0, stream>>>(Bs, zdup1, xsw1, dst, acc);
    k_combine<256, 12><<<EN * 256 / 256, 256, 0, stream>>>(acc, S, x, b1b, root1, bias1, cntE, x, d1);

    // ---- layer 2 (I=268 -> pad 288, O=256) ----
    hipMemsetAsync(acc, 0, accS_bytes, stream);
    k_gatherw<9, 32, 268><<<EN * 288 / 256, 256, 0, stream>>>(d1, src, dst, xsw2, S);
    k_swz<256, 268, 9, 32><<<dim3(512, 18), 256, 0, stream>>>(W2b, Bs);
    edge_gemm<512, 256, 9, 32, 13><<<dim3(6, 2, 42), 256, 0, stream>>>(Bs, zdup2, xsw2, dst, acc);
    k_combine<256, 268><<<EN * 256 / 256, 256, 0, stream>>>(acc, S, d1, b2b, root2, bias2, cntE, x, d2);

    // ---- layer 3 (I=268 -> pad 288, O=512) ----
    hipMemsetAsync(acc, 0, accS_bytes, stream);
    k_gatherw<9, 32, 268><<<EN * 288 / 256, 256, 0, stream>>>(d2, src, dst, xsw3, S);
    k_swz<512, 268, 9, 32><<<dim3(512, 36), 256, 0, stream>>>(W3b, Bs);
    edge_gemm<512, 512, 9, 32, 25><<<dim3(6, 4, 21), 256, 0, stream>>>(Bs, zdup3, xsw3, dst, acc);
    k_combine<512, 268><<<EN * 512 / 256, 256, 0, stream>>>(acc, S, d2, b3b, root3, bias3, cntE, x, d3);

    // ---- head ----
    hipMemsetAsync(pooled, 0, (size_t)NG * 524 * 4, stream);
    k_pool<<<EN * 524 / 256, 256, 0, stream>>>(d3, batch, pooled);
    k_fc<524, 768, true, true><<<NG * 768 / 256, 256, 0, stream>>>(pooled, fc1W, fc1b, cntg, fc1o);
    k_fc<768, 1024, true, false><<<NG * 1024 / 256, 256, 0, stream>>>(fc1o, fc2W, fc2b, nullptr, fc2o);
    k_fc3r<<<NG, 256, 0, stream>>>(fc2o, fc3W, fc3b, out);
}